// Round 1
// baseline (722.734 us; speedup 1.0000x reference)
//
#include <hip/hip_runtime.h>
#include <hip/hip_bf16.h>

typedef __attribute__((ext_vector_type(8))) short short8;
typedef __attribute__((ext_vector_type(4))) float f32x4;

#define GLD16(gp, lp) __builtin_amdgcn_global_load_lds( \
    (const __attribute__((address_space(1))) unsigned int*)(gp), \
    (__attribute__((address_space(3))) unsigned int*)(lp), 16, 0, 0)

static __device__ __forceinline__ float bf2f(unsigned short u) {
    union { unsigned int i; float f; } v; v.i = ((unsigned int)u) << 16; return v.f;
}
static __device__ __forceinline__ short f2bf(float f) {
    union { float f; unsigned int i; } v; v.f = f;
    unsigned int r = v.i + 0x7FFFu + ((v.i >> 16) & 1u);
    return (short)(r >> 16);
}

// ---------------- elementwise cast fp32 -> bf16 ----------------
__global__ void cast_f32_bf16(const float* __restrict__ src, short* __restrict__ dst, int n) {
    int i = (blockIdx.x * 256 + threadIdx.x) * 4;
    if (i >= n) return;
    float4 v = *(const float4*)(src + i);
    short4 o;
    o.x = f2bf(v.x); o.y = f2bf(v.y); o.z = f2bf(v.z); o.w = f2bf(v.w);
    *(short4*)(dst + i) = o;
}

// ---------------- transpose+cast: src fp32 (K x N) -> dst bf16 (N x K), dst row stride = dstStride ----------------
__global__ void transpose_cast(const float* __restrict__ src, short* __restrict__ dst,
                               int N, int dstStride) {
    __shared__ float tile[32][33];
    int k0 = blockIdx.x * 32, n0 = blockIdx.y * 32;
    int t = threadIdx.x, c = t & 31, r = t >> 5;
#pragma unroll
    for (int p = 0; p < 4; ++p)
        tile[r + p * 8][c] = src[(size_t)(k0 + r + p * 8) * N + n0 + c];
    __syncthreads();
#pragma unroll
    for (int p = 0; p < 4; ++p)
        dst[(size_t)(n0 + r + p * 8) * dstStride + k0 + c] = f2bf(tile[c][r + p * 8]);
}

// ---------------- transpose V (bf16, strided src in QKV) -> Vt [b][kvh][128][2048] ----------------
__global__ void transpose_v(const short* __restrict__ qkv, short* __restrict__ vt) {
    __shared__ short tile[32][33];
    int s0 = blockIdx.x * 32, d0 = blockIdx.y * 32;
    int bh = blockIdx.z;
    int b = bh >> 3, h = bh & 7;
    const short* src = qkv + (size_t)b * 2048 * 6144 + 5120 + h * 128;
    short* dst = vt + (size_t)bh * 128 * 2048;
    int t = threadIdx.x, c = t & 31, r = t >> 5;
#pragma unroll
    for (int p = 0; p < 4; ++p)
        tile[r + p * 8][c] = src[(size_t)(s0 + r + p * 8) * 6144 + d0 + c];
    __syncthreads();
#pragma unroll
    for (int p = 0; p < 4; ++p)
        dst[(size_t)(d0 + r + p * 8) * 2048 + s0 + c] = tile[c][r + p * 8];
}

// ---------------- rope tables: [2048][64][2] (cos,sin) ----------------
__global__ void rope_tables(float* __restrict__ cs) {
    int i = blockIdx.x * 256 + threadIdx.x;  // 2048*64
    int s = i >> 6, d2 = i & 63;
    float inv = expf(-9.210340371976184f * (float)(2 * d2) * (1.0f / 128.0f)); // 10000^(-2i/128)
    float ang = (float)s * inv;
    float sn, c;
    sincosf(ang, &sn, &c);
    cs[(size_t)i * 2] = c;
    cs[(size_t)i * 2 + 1] = sn;
}

// ---------------- rope apply + regroup: QKV[b][s][colOff+h*128+d] -> dst[b][h][s][d] ----------------
template<int NH>
__global__ void rope_apply(const short* __restrict__ qkv, const float* __restrict__ cs,
                           short* __restrict__ dst, int colOff, float scale) {
    int i = blockIdx.x * 256 + threadIdx.x;
    int d2 = i & 63;
    int t2 = i >> 6;
    int h = t2 % NH;
    int bs = t2 / NH;        // b*2048 + s
    int s = bs & 2047;
    int b = bs >> 11;
    unsigned int pr = *(const unsigned int*)(qkv + (size_t)bs * 6144 + colOff + h * 128 + 2 * d2);
    float xr = bf2f((unsigned short)(pr & 0xFFFFu));
    float xi = bf2f((unsigned short)(pr >> 16));
    const float* cp = cs + ((size_t)s * 64 + d2) * 2;
    float c = cp[0], sn = cp[1];
    float outr = (xr * c - xi * sn) * scale;
    float outi = (xr * sn + xi * c) * scale;
    unsigned int po = ((unsigned int)(unsigned short)f2bf(outi) << 16) | (unsigned int)(unsigned short)f2bf(outr);
    *(unsigned int*)(dst + ((size_t)(b * NH + h) * 2048 + s) * 128 + 2 * d2) = po;
}

// ---------------- GEMM: A bf16 (M x K) row-major, Bt bf16 (N x K) row-major, C = A*B ----------------
// 128x128 tile, BK=64, 4 waves each 64x64. XOR-swizzled LDS (byte ^= (row&7)<<4), swizzle on global source.
template<bool BF16OUT>
__global__ __launch_bounds__(256, 2) void gemm_bt(const short* __restrict__ A,
                                                  const short* __restrict__ Bt,
                                                  void* __restrict__ Cv,
                                                  int N, int K) {
    __shared__ short As[128 * 64];
    __shared__ short Bs[128 * 64];
    const int tid = threadIdx.x;
    const int lane = tid & 63;
    const int wid = tid >> 6;
    const int lr = lane & 15;
    const int lq = lane >> 4;
    const int m0 = blockIdx.x * 128;
    const int n0 = blockIdx.y * 128;
    const int wr = (wid >> 1) * 64;
    const int wc = (wid & 1) * 64;
    f32x4 acc[4][4];
#pragma unroll
    for (int i = 0; i < 4; ++i)
#pragma unroll
        for (int j = 0; j < 4; ++j) acc[i][j] = f32x4{0.f, 0.f, 0.f, 0.f};

    const short* aBase = A + (size_t)m0 * K;
    const short* bBase = Bt + (size_t)n0 * K;

    for (int k0 = 0; k0 < K; k0 += 64) {
#pragma unroll
        for (int j = 0; j < 4; ++j) {
            int c = (wid * 4 + j) * 64 + lane;
            int row = c >> 3;                                   // 8x16B chunks per 128B row
            int cb = ((c & 7) << 4) ^ ((row & 7) << 4);         // inverse-swizzled source col (bytes)
            GLD16(aBase + (size_t)row * K + k0 + (cb >> 1), As + (wid * 4 + j) * 512);
            GLD16(bBase + (size_t)row * K + k0 + (cb >> 1), Bs + (wid * 4 + j) * 512);
        }
        __syncthreads();
#pragma unroll
        for (int ks = 0; ks < 2; ++ks) {
            short8 af[4], bfr[4];
#pragma unroll
            for (int mi = 0; mi < 4; ++mi) {
                int row = wr + mi * 16 + lr;
                int cb = (ks * 64 + lq * 16) ^ ((row & 7) << 4);
                af[mi] = *(const short8*)(As + row * 64 + (cb >> 1));
            }
#pragma unroll
            for (int ni = 0; ni < 4; ++ni) {
                int row = wc + ni * 16 + lr;
                int cb = (ks * 64 + lq * 16) ^ ((row & 7) << 4);
                bfr[ni] = *(const short8*)(Bs + row * 64 + (cb >> 1));
            }
#pragma unroll
            for (int mi = 0; mi < 4; ++mi)
#pragma unroll
                for (int ni = 0; ni < 4; ++ni)
                    acc[mi][ni] = __builtin_amdgcn_mfma_f32_16x16x32_bf16(af[mi], bfr[ni], acc[mi][ni], 0, 0, 0);
        }
        __syncthreads();
    }
#pragma unroll
    for (int mi = 0; mi < 4; ++mi)
#pragma unroll
        for (int ni = 0; ni < 4; ++ni)
#pragma unroll
            for (int r = 0; r < 4; ++r) {
                int row = m0 + wr + mi * 16 + lq * 4 + r;
                int col = n0 + wc + ni * 16 + lr;
                float v = acc[mi][ni][r];
                if constexpr (BF16OUT) ((short*)Cv)[(size_t)row * N + col] = f2bf(v);
                else                   ((float*)Cv)[(size_t)row * N + col] = v;
            }
}

// ---------------- flash attention: Qr[b][qh][s][128] (pre-scaled), Kr[b][kvh][s][128], Vt[b][kvh][128][2048] ----------------
// grid (32 qblocks, 64 b*qh), 4 waves x 16 q-rows, KVBLK=64, causal.
__global__ __launch_bounds__(256, 2) void attn_kernel(const short* __restrict__ Qr,
                                                      const short* __restrict__ Kr,
                                                      const short* __restrict__ Vt,
                                                      short* __restrict__ Out) {
    __shared__ short Ks[64 * 128];   // [kv][d], swizzled 256B rows
    __shared__ short Vs[128 * 64];   // [d][kv], swizzled 128B rows
    __shared__ short Ps[4 * 1024];   // per-wave [16][64], swizzled 128B rows
    const int qb = blockIdx.x;
    const int bh = blockIdx.y;
    const int b = bh >> 5;
    const int qh = bh & 31;
    const int kvh = qh >> 2;
    const int tid = threadIdx.x;
    const int lane = tid & 63;
    const int wid = tid >> 6;
    const int lr = lane & 15;
    const int lq = lane >> 4;

    const short* qbase = Qr + ((size_t)bh * 2048 + qb * 64 + wid * 16) * 128;
    short8 qf[4];
#pragma unroll
    for (int ks = 0; ks < 4; ++ks)
        qf[ks] = *(const short8*)(qbase + lr * 128 + ks * 32 + lq * 8);

    const short* kbase = Kr + (size_t)(b * 8 + kvh) * 2048 * 128;
    const short* vbase = Vt + (size_t)(b * 8 + kvh) * 128 * 2048;

    float m_run[4], l_run[4];
    f32x4 o_acc[8];
#pragma unroll
    for (int r = 0; r < 4; ++r) { m_run[r] = -INFINITY; l_run[r] = 0.0f; }
#pragma unroll
    for (int d = 0; d < 8; ++d) o_acc[d] = f32x4{0.f, 0.f, 0.f, 0.f};

    short* pw = Ps + wid * 1024;
    const int nkb = qb + 1;
    for (int kb = 0; kb < nkb; ++kb) {
        const int s0 = kb * 64;
#pragma unroll
        for (int j = 0; j < 4; ++j) {
            int c = (wid * 4 + j) * 64 + lane;
            int krow = c >> 4;                                   // 16 chunks per 256B row
            int kcb = ((c & 15) << 4) ^ ((krow & 7) << 4);
            GLD16(kbase + (size_t)(s0 + krow) * 128 + (kcb >> 1), Ks + (wid * 4 + j) * 512);
            int vrow = c >> 3;                                   // 8 chunks per 128B row
            int vcb = ((c & 7) << 4) ^ ((vrow & 7) << 4);
            GLD16(vbase + (size_t)vrow * 2048 + s0 + (vcb >> 1), Vs + (wid * 4 + j) * 512);
        }
        __syncthreads();

        f32x4 s_acc[4];
#pragma unroll
        for (int ct = 0; ct < 4; ++ct) s_acc[ct] = f32x4{0.f, 0.f, 0.f, 0.f};
#pragma unroll
        for (int ct = 0; ct < 4; ++ct) {
#pragma unroll
            for (int ks = 0; ks < 4; ++ks) {
                int row = ct * 16 + lr;
                int cb = (ks * 64 + lq * 16) ^ ((row & 7) << 4);
                short8 kf = *(const short8*)(Ks + row * 128 + (cb >> 1));
                s_acc[ct] = __builtin_amdgcn_mfma_f32_16x16x32_bf16(qf[ks], kf, s_acc[ct], 0, 0, 0);
            }
        }

        if (kb == qb) {  // diagonal block: mask col > row
            const int rowg = wid * 16 + lq * 4;
#pragma unroll
            for (int ct = 0; ct < 4; ++ct)
#pragma unroll
                for (int r = 0; r < 4; ++r)
                    if (ct * 16 + lr > rowg + r) s_acc[ct][r] = -INFINITY;
        }

#pragma unroll
        for (int r = 0; r < 4; ++r) {
            const int rowi = lq * 4 + r;
            float mx = fmaxf(fmaxf(s_acc[0][r], s_acc[1][r]), fmaxf(s_acc[2][r], s_acc[3][r]));
#pragma unroll
            for (int o = 1; o < 16; o <<= 1) mx = fmaxf(mx, __shfl_xor(mx, o, 64));
            float mN = fmaxf(m_run[r], mx);
            float alpha = __expf(m_run[r] - mN);
            float rsum = 0.0f;
#pragma unroll
            for (int ct = 0; ct < 4; ++ct) {
                float p = __expf(s_acc[ct][r] - mN);
                rsum += p;
                pw[(rowi * 128 + (((ct * 16 + lr) << 1) ^ ((rowi & 7) << 4))) >> 1] = f2bf(p);
            }
#pragma unroll
            for (int o = 1; o < 16; o <<= 1) rsum += __shfl_xor(rsum, o, 64);
            m_run[r] = mN;
            l_run[r] = l_run[r] * alpha + rsum;
#pragma unroll
            for (int dt = 0; dt < 8; ++dt) o_acc[dt][r] *= alpha;
        }

        short8 pa[2];
#pragma unroll
        for (int kk = 0; kk < 2; ++kk)
            pa[kk] = *(const short8*)(pw + ((lr * 128 + ((kk * 64 + lq * 16) ^ ((lr & 7) << 4))) >> 1));
#pragma unroll
        for (int dt = 0; dt < 8; ++dt) {
#pragma unroll
            for (int kk = 0; kk < 2; ++kk) {
                int row = dt * 16 + lr;
                int cb = (kk * 64 + lq * 16) ^ ((row & 7) << 4);
                short8 vf = *(const short8*)(Vs + row * 64 + (cb >> 1));
                o_acc[dt] = __builtin_amdgcn_mfma_f32_16x16x32_bf16(pa[kk], vf, o_acc[dt], 0, 0, 0);
            }
        }
        __syncthreads();
    }

    const size_t orow0 = (size_t)b * 2048 + qb * 64 + wid * 16;
#pragma unroll
    for (int r = 0; r < 4; ++r) {
        float inv = 1.0f / l_run[r];
#pragma unroll
        for (int dt = 0; dt < 8; ++dt) {
            size_t row = orow0 + lq * 4 + r;
            Out[row * 4096 + qh * 128 + dt * 16 + lr] = f2bf(o_acc[dt][r] * inv);
        }
    }
}

// ---------------- workspace layout (bytes) ----------------
// WT_QKV  @ 0          : 6144x4096 bf16 = 50331648
// XB      @ 50331648   : 4096x4096 bf16 = 33554432   (reused as attn output)
// QKV     @ 83886080   : 4096x6144 bf16 = 50331648   (first 33.5MB reused as WT_O)
// QR      @ 134217728  : 2*32*2048*128 bf16 = 33554432
// KR      @ 167772160  : 2*8*2048*128 bf16 = 8388608
// VT      @ 176160768  : 2*8*128*2048 bf16 = 8388608
// TAB     @ 184549376  : 2048*64*2 fp32 = 1048576    -> total 185597952

extern "C" void kernel_launch(void* const* d_in, const int* in_sizes, int n_in,
                              void* d_out, int out_size, void* d_ws, size_t ws_size,
                              hipStream_t stream) {
    const float* x  = (const float*)d_in[0];
    const float* wq = (const float*)d_in[1];
    const float* wk = (const float*)d_in[2];
    const float* wv = (const float*)d_in[3];
    const float* wo = (const float*)d_in[4];
    float* out = (float*)d_out;
    char* ws = (char*)d_ws;

    short* wt_qkv = (short*)(ws + 0);
    short* xb     = (short*)(ws + 50331648);
    short* qkv    = (short*)(ws + 83886080);
    short* wt_o   = (short*)(ws + 83886080);   // aliases QKV (used after QKV is dead)
    short* qr     = (short*)(ws + 134217728);
    short* kr     = (short*)(ws + 167772160);
    short* vt     = (short*)(ws + 176160768);
    float* tab    = (float*)(ws + 184549376);

    // 1. cast x -> bf16
    cast_f32_bf16<<<16384, 256, 0, stream>>>(x, xb, 16777216);
    // 2. transpose-cast weights into fused Wqkv^T (6144 x 4096)
    transpose_cast<<<dim3(128, 128), 256, 0, stream>>>(wq, wt_qkv, 4096, 4096);
    transpose_cast<<<dim3(128, 32),  256, 0, stream>>>(wk, wt_qkv + (size_t)4096 * 4096, 1024, 4096);
    transpose_cast<<<dim3(128, 32),  256, 0, stream>>>(wv, wt_qkv + (size_t)5120 * 4096, 1024, 4096);
    // 3. rope tables
    rope_tables<<<512, 256, 0, stream>>>(tab);
    // 4. fused QKV GEMM -> qkv bf16 (4096 x 6144)
    gemm_bt<true><<<dim3(32, 48), 256, 0, stream>>>(xb, wt_qkv, (void*)qkv, 6144, 4096);
    // 5. rope+regroup Q (scale folded) and K; transpose V
    rope_apply<32><<<32768, 256, 0, stream>>>(qkv, tab, qr, 0, 0.08838834764831845f);
    rope_apply<8><<<8192, 256, 0, stream>>>(qkv, tab, kr, 4096, 1.0f);
    transpose_v<<<dim3(64, 4, 16), 256, 0, stream>>>(qkv, vt);
    // 6. wo^T cast (into dead QKV region)
    transpose_cast<<<dim3(128, 128), 256, 0, stream>>>(wo, wt_o, 4096, 4096);
    // 7. flash attention -> xb (reused, bf16 [b*s][4096])
    attn_kernel<<<dim3(32, 64), 256, 0, stream>>>(qr, kr, vt, xb);
    // 8. output projection -> d_out fp32
    gemm_bt<false><<<dim3(32, 32), 256, 0, stream>>>(xb, wt_o, (void*)out, 4096, 4096);
}

// Round 2
// 638.758 us; speedup vs baseline: 1.1315x; 1.1315x over previous
//
#include <hip/hip_runtime.h>
#include <hip/hip_bf16.h>

typedef __attribute__((ext_vector_type(8))) short short8;
typedef __attribute__((ext_vector_type(4))) float f32x4;

#define GLD16(gp, lp) __builtin_amdgcn_global_load_lds( \
    (const __attribute__((address_space(1))) unsigned int*)(gp), \
    (__attribute__((address_space(3))) unsigned int*)(lp), 16, 0, 0)

static __device__ __forceinline__ float bf2f(unsigned short u) {
    union { unsigned int i; float f; } v; v.i = ((unsigned int)u) << 16; return v.f;
}
static __device__ __forceinline__ short f2bf(float f) {
    union { float f; unsigned int i; } v; v.f = f;
    unsigned int r = v.i + 0x7FFFu + ((v.i >> 16) & 1u);
    return (short)(r >> 16);
}
static __device__ __forceinline__ unsigned int pack2bf(float lo, float hi) {
    return ((unsigned int)(unsigned short)f2bf(hi) << 16) | (unsigned int)(unsigned short)f2bf(lo);
}

// ---------------- elementwise cast fp32 -> bf16 ----------------
__global__ void cast_f32_bf16(const float* __restrict__ src, short* __restrict__ dst, int n) {
    int i = (blockIdx.x * 256 + threadIdx.x) * 4;
    if (i >= n) return;
    float4 v = *(const float4*)(src + i);
    short4 o;
    o.x = f2bf(v.x); o.y = f2bf(v.y); o.z = f2bf(v.z); o.w = f2bf(v.w);
    *(short4*)(dst + i) = o;
}

// ---------------- transpose+cast: src fp32 (K x N) -> dst bf16 (N x K) ----------------
__global__ void transpose_cast(const float* __restrict__ src, short* __restrict__ dst,
                               int N, int dstStride) {
    __shared__ float tile[32][33];
    int k0 = blockIdx.x * 32, n0 = blockIdx.y * 32;
    int t = threadIdx.x, c = t & 31, r = t >> 5;
#pragma unroll
    for (int p = 0; p < 4; ++p)
        tile[r + p * 8][c] = src[(size_t)(k0 + r + p * 8) * N + n0 + c];
    __syncthreads();
#pragma unroll
    for (int p = 0; p < 4; ++p)
        dst[(size_t)(n0 + r + p * 8) * dstStride + k0 + c] = f2bf(tile[c][r + p * 8]);
}

// ---------------- transpose V (bf16, strided src in QKV) -> Vt [b][kvh][128][2048] ----------------
__global__ void transpose_v(const short* __restrict__ qkv, short* __restrict__ vt) {
    __shared__ short tile[32][33];
    int s0 = blockIdx.x * 32, d0 = blockIdx.y * 32;
    int bh = blockIdx.z;
    int b = bh >> 3, h = bh & 7;
    const short* src = qkv + (size_t)b * 2048 * 6144 + 5120 + h * 128;
    short* dst = vt + (size_t)bh * 128 * 2048;
    int t = threadIdx.x, c = t & 31, r = t >> 5;
#pragma unroll
    for (int p = 0; p < 4; ++p)
        tile[r + p * 8][c] = src[(size_t)(s0 + r + p * 8) * 6144 + d0 + c];
    __syncthreads();
#pragma unroll
    for (int p = 0; p < 4; ++p)
        dst[(size_t)(d0 + r + p * 8) * 2048 + s0 + c] = tile[c][r + p * 8];
}

// ---------------- rope tables: [2048][64][2] (cos,sin) ----------------
__global__ void rope_tables(float* __restrict__ cs) {
    int i = blockIdx.x * 256 + threadIdx.x;
    int s = i >> 6, d2 = i & 63;
    float inv = expf(-9.210340371976184f * (float)(2 * d2) * (1.0f / 128.0f));
    float ang = (float)s * inv;
    float sn, c;
    sincosf(ang, &sn, &c);
    cs[(size_t)i * 2] = c;
    cs[(size_t)i * 2 + 1] = sn;
}

// ---------------- rope apply + regroup ----------------
template<int NH>
__global__ void rope_apply(const short* __restrict__ qkv, const float* __restrict__ cs,
                           short* __restrict__ dst, int colOff, float scale) {
    int i = blockIdx.x * 256 + threadIdx.x;
    int d2 = i & 63;
    int t2 = i >> 6;
    int h = t2 % NH;
    int bs = t2 / NH;
    int s = bs & 2047;
    int b = bs >> 11;
    unsigned int pr = *(const unsigned int*)(qkv + (size_t)bs * 6144 + colOff + h * 128 + 2 * d2);
    float xr = bf2f((unsigned short)(pr & 0xFFFFu));
    float xi = bf2f((unsigned short)(pr >> 16));
    const float* cp = cs + ((size_t)s * 64 + d2) * 2;
    float c = cp[0], sn = cp[1];
    float outr = (xr * c - xi * sn) * scale;
    float outi = (xr * sn + xi * c) * scale;
    *(unsigned int*)(dst + ((size_t)(b * NH + h) * 2048 + s) * 128 + 2 * d2) = pack2bf(outr, outi);
}

// ---------------- GEMM: A bf16 (M x K) row-major, Bt bf16 (N x K) row-major, C = A*B ----------------
template<bool BF16OUT>
__global__ __launch_bounds__(256, 2) void gemm_bt(const short* __restrict__ A,
                                                  const short* __restrict__ Bt,
                                                  void* __restrict__ Cv,
                                                  int N, int K) {
    __shared__ short As[128 * 64];
    __shared__ short Bs[128 * 64];
    const int tid = threadIdx.x;
    const int lane = tid & 63;
    const int wid = tid >> 6;
    const int lr = lane & 15;
    const int lq = lane >> 4;
    const int m0 = blockIdx.x * 128;
    const int n0 = blockIdx.y * 128;
    const int wr = (wid >> 1) * 64;
    const int wc = (wid & 1) * 64;
    f32x4 acc[4][4];
#pragma unroll
    for (int i = 0; i < 4; ++i)
#pragma unroll
        for (int j = 0; j < 4; ++j) acc[i][j] = f32x4{0.f, 0.f, 0.f, 0.f};

    const short* aBase = A + (size_t)m0 * K;
    const short* bBase = Bt + (size_t)n0 * K;

    for (int k0 = 0; k0 < K; k0 += 64) {
#pragma unroll
        for (int j = 0; j < 4; ++j) {
            int c = (wid * 4 + j) * 64 + lane;
            int row = c >> 3;
            int cb = ((c & 7) << 4) ^ ((row & 7) << 4);
            GLD16(aBase + (size_t)row * K + k0 + (cb >> 1), As + (wid * 4 + j) * 512);
            GLD16(bBase + (size_t)row * K + k0 + (cb >> 1), Bs + (wid * 4 + j) * 512);
        }
        __syncthreads();
#pragma unroll
        for (int ks = 0; ks < 2; ++ks) {
            short8 af[4], bfr[4];
#pragma unroll
            for (int mi = 0; mi < 4; ++mi) {
                int row = wr + mi * 16 + lr;
                int cb = (ks * 64 + lq * 16) ^ ((row & 7) << 4);
                af[mi] = *(const short8*)(As + row * 64 + (cb >> 1));
            }
#pragma unroll
            for (int ni = 0; ni < 4; ++ni) {
                int row = wc + ni * 16 + lr;
                int cb = (ks * 64 + lq * 16) ^ ((row & 7) << 4);
                bfr[ni] = *(const short8*)(Bs + row * 64 + (cb >> 1));
            }
#pragma unroll
            for (int mi = 0; mi < 4; ++mi)
#pragma unroll
                for (int ni = 0; ni < 4; ++ni)
                    acc[mi][ni] = __builtin_amdgcn_mfma_f32_16x16x32_bf16(af[mi], bfr[ni], acc[mi][ni], 0, 0, 0);
        }
        __syncthreads();
    }
#pragma unroll
    for (int mi = 0; mi < 4; ++mi)
#pragma unroll
        for (int ni = 0; ni < 4; ++ni)
#pragma unroll
            for (int r = 0; r < 4; ++r) {
                int row = m0 + wr + mi * 16 + lq * 4 + r;
                int col = n0 + wc + ni * 16 + lr;
                float v = acc[mi][ni][r];
                if constexpr (BF16OUT) ((short*)Cv)[(size_t)row * N + col] = f2bf(v);
                else                   ((float*)Cv)[(size_t)row * N + col] = v;
            }
}

// ---------------- flash attention, swapped-QK^T softmax ----------------
// Qr[b][qh][s][128] pre-scaled, Kr[b][kvh][s][128], Vt[b][kvh][128][2048]
// grid (32 qblocks, 64 b*qh), 4 waves x 16 q-rows, KVBLK=64, causal.
// S^T = mfma(K, Q): lane holds P[q=lane&15][kv = ct*16 + lq*4 + r] -> softmax mostly lane-local.
__global__ __launch_bounds__(256, 4) void attn_kernel(const short* __restrict__ Qr,
                                                      const short* __restrict__ Kr,
                                                      const short* __restrict__ Vt,
                                                      short* __restrict__ Out) {
    __shared__ short Ks[64 * 128];   // [kv][d], swizzled 256B rows
    __shared__ short Vs[128 * 64];   // [d][kv], swizzled 128B rows
    __shared__ short Ps[4 * 1024];   // per-wave [16 q][64 kv], swizzled 128B rows
    const int qb = 31 - blockIdx.x;  // long blocks dispatch first (load balance)
    const int bh = blockIdx.y;
    const int b = bh >> 5;
    const int qh = bh & 31;
    const int kvh = qh >> 2;
    const int tid = threadIdx.x;
    const int lane = tid & 63;
    const int wid = tid >> 6;
    const int lr = lane & 15;
    const int lq = lane >> 4;

    const short* qbase = Qr + ((size_t)bh * 2048 + qb * 64 + wid * 16) * 128;
    short8 qf[4];
#pragma unroll
    for (int ks = 0; ks < 4; ++ks)
        qf[ks] = *(const short8*)(qbase + lr * 128 + ks * 32 + lq * 8);

    const short* kbase = Kr + (size_t)(b * 8 + kvh) * 2048 * 128;
    const short* vbase = Vt + (size_t)(b * 8 + kvh) * 128 * 2048;

    float m_run = -INFINITY, l_run = 0.0f;   // keyed by q-row = lr (replicated over lq)
    f32x4 o_acc[8];                           // O rows = lq*4+r, col d = dt*16+lr
#pragma unroll
    for (int d = 0; d < 8; ++d) o_acc[d] = f32x4{0.f, 0.f, 0.f, 0.f};

    short* pw = Ps + wid * 1024;
    for (int kb = 0; kb <= qb; ++kb) {
        const int s0 = kb * 64;
#pragma unroll
        for (int j = 0; j < 4; ++j) {
            int c = (wid * 4 + j) * 64 + lane;
            int krow = c >> 4;
            int kcb = ((c & 15) << 4) ^ ((krow & 7) << 4);
            GLD16(kbase + (size_t)(s0 + krow) * 128 + (kcb >> 1), Ks + (wid * 4 + j) * 512);
            int vrow = c >> 3;
            int vcb = ((c & 7) << 4) ^ ((vrow & 7) << 4);
            GLD16(vbase + (size_t)vrow * 2048 + s0 + (vcb >> 1), Vs + (wid * 4 + j) * 512);
        }
        __syncthreads();

        // S^T[kv][q]: swapped operand order
        f32x4 st[4];
#pragma unroll
        for (int ct = 0; ct < 4; ++ct) st[ct] = f32x4{0.f, 0.f, 0.f, 0.f};
#pragma unroll
        for (int ct = 0; ct < 4; ++ct) {
#pragma unroll
            for (int ks = 0; ks < 4; ++ks) {
                int row = ct * 16 + lr;
                int cb = (ks * 64 + lq * 16) ^ ((row & 7) << 4);
                short8 kf = *(const short8*)(Ks + row * 128 + (cb >> 1));
                st[ct] = __builtin_amdgcn_mfma_f32_16x16x32_bf16(kf, qf[ks], st[ct], 0, 0, 0);
            }
        }

        if (kb == qb) {  // diagonal: mask kv > q (local coords: both offset by qb*64)
#pragma unroll
            for (int ct = 0; ct < 4; ++ct)
#pragma unroll
                for (int r = 0; r < 4; ++r)
                    if (ct * 16 + lq * 4 + r > wid * 16 + lr) st[ct][r] = -INFINITY;
        }

        // row max: 16 in-lane + 2 shuffles
        float mx = fmaxf(fmaxf(fmaxf(st[0][0], st[0][1]), fmaxf(st[0][2], st[0][3])),
                         fmaxf(fmaxf(st[1][0], st[1][1]), fmaxf(st[1][2], st[1][3])));
        mx = fmaxf(mx, fmaxf(fmaxf(fmaxf(st[2][0], st[2][1]), fmaxf(st[2][2], st[2][3])),
                             fmaxf(fmaxf(st[3][0], st[3][1]), fmaxf(st[3][2], st[3][3]))));
        mx = fmaxf(mx, __shfl_xor(mx, 16, 64));
        mx = fmaxf(mx, __shfl_xor(mx, 32, 64));

        // defer-max (T13, THR=8): skip rescale when growth is small
        const bool defer = __all(mx - m_run <= 8.0f);
        float mN, alpha;
        if (defer) { mN = m_run; alpha = 1.0f; }
        else       { mN = fmaxf(m_run, mx); alpha = __expf(m_run - mN); }

        float p[4][4];
        float rsum = 0.0f;
#pragma unroll
        for (int ct = 0; ct < 4; ++ct)
#pragma unroll
            for (int r = 0; r < 4; ++r) {
                p[ct][r] = __expf(st[ct][r] - mN);
                rsum += p[ct][r];
            }
        rsum += __shfl_xor(rsum, 16, 64);
        rsum += __shfl_xor(rsum, 32, 64);
        l_run = l_run * alpha + rsum;
        m_run = mN;

        // pack P -> LDS (b64 writes, swizzled): row q=lr, kv cols ct*16+lq*4..+3
#pragma unroll
        for (int ct = 0; ct < 4; ++ct) {
            uint2 w;
            w.x = pack2bf(p[ct][0], p[ct][1]);
            w.y = pack2bf(p[ct][2], p[ct][3]);
            int off = (ct * 32 + lq * 8) ^ ((lr & 7) << 4);
            *(uint2*)(pw + ((lr * 128 + off) >> 1)) = w;
        }

        // rescale O (rows lq*4+r need alpha of row lq*4+r, held at lane lq*4+r)
        if (!defer) {
            float av[4];
#pragma unroll
            for (int r = 0; r < 4; ++r) av[r] = __shfl(alpha, lq * 4 + r, 64);
#pragma unroll
            for (int dt = 0; dt < 8; ++dt)
#pragma unroll
                for (int r = 0; r < 4; ++r) o_acc[dt][r] *= av[r];
        }

        // PV: A = P[16q x 32kv] from Ps, B = V[32kv x 16d] from Vs
        short8 pa[2];
#pragma unroll
        for (int kk = 0; kk < 2; ++kk)
            pa[kk] = *(const short8*)(pw + ((lr * 128 + ((kk * 64 + lq * 16) ^ ((lr & 7) << 4))) >> 1));
#pragma unroll
        for (int dt = 0; dt < 8; ++dt) {
#pragma unroll
            for (int kk = 0; kk < 2; ++kk) {
                int row = dt * 16 + lr;
                int cb = (kk * 64 + lq * 16) ^ ((row & 7) << 4);
                short8 vf = *(const short8*)(Vs + row * 64 + (cb >> 1));
                o_acc[dt] = __builtin_amdgcn_mfma_f32_16x16x32_bf16(pa[kk], vf, o_acc[dt], 0, 0, 0);
            }
        }
        __syncthreads();
    }

    // epilogue: fetch l for this lane's O rows, normalize, store
    float lrow[4];
#pragma unroll
    for (int r = 0; r < 4; ++r) lrow[r] = __shfl(l_run, lq * 4 + r, 64);
    const size_t orow0 = (size_t)b * 2048 + qb * 64 + wid * 16;
#pragma unroll
    for (int r = 0; r < 4; ++r) {
        float inv = 1.0f / lrow[r];
#pragma unroll
        for (int dt = 0; dt < 8; ++dt) {
            size_t row = orow0 + lq * 4 + r;
            Out[row * 4096 + qh * 128 + dt * 16 + lr] = f2bf(o_acc[dt][r] * inv);
        }
    }
}

// ---------------- workspace layout (bytes) ----------------
// WT_QKV  @ 0          : 6144x4096 bf16 = 50331648
// XB      @ 50331648   : 4096x4096 bf16 = 33554432   (reused as attn output)
// QKV     @ 83886080   : 4096x6144 bf16 = 50331648   (first 33.5MB reused as WT_O)
// QR      @ 134217728  : 2*32*2048*128 bf16 = 33554432
// KR      @ 167772160  : 2*8*2048*128 bf16 = 8388608
// VT      @ 176160768  : 2*8*128*2048 bf16 = 8388608
// TAB     @ 184549376  : 2048*64*2 fp32 = 1048576    -> total 185597952

extern "C" void kernel_launch(void* const* d_in, const int* in_sizes, int n_in,
                              void* d_out, int out_size, void* d_ws, size_t ws_size,
                              hipStream_t stream) {
    const float* x  = (const float*)d_in[0];
    const float* wq = (const float*)d_in[1];
    const float* wk = (const float*)d_in[2];
    const float* wv = (const float*)d_in[3];
    const float* wo = (const float*)d_in[4];
    float* out = (float*)d_out;
    char* ws = (char*)d_ws;

    short* wt_qkv = (short*)(ws + 0);
    short* xb     = (short*)(ws + 50331648);
    short* qkv    = (short*)(ws + 83886080);
    short* wt_o   = (short*)(ws + 83886080);
    short* qr     = (short*)(ws + 134217728);
    short* kr     = (short*)(ws + 167772160);
    short* vt     = (short*)(ws + 176160768);
    float* tab    = (float*)(ws + 184549376);

    cast_f32_bf16<<<16384, 256, 0, stream>>>(x, xb, 16777216);
    transpose_cast<<<dim3(128, 128), 256, 0, stream>>>(wq, wt_qkv, 4096, 4096);
    transpose_cast<<<dim3(128, 32),  256, 0, stream>>>(wk, wt_qkv + (size_t)4096 * 4096, 1024, 4096);
    transpose_cast<<<dim3(128, 32),  256, 0, stream>>>(wv, wt_qkv + (size_t)5120 * 4096, 1024, 4096);
    rope_tables<<<512, 256, 0, stream>>>(tab);
    gemm_bt<true><<<dim3(32, 48), 256, 0, stream>>>(xb, wt_qkv, (void*)qkv, 6144, 4096);
    rope_apply<32><<<32768, 256, 0, stream>>>(qkv, tab, qr, 0, 0.08838834764831845f);
    rope_apply<8><<<8192, 256, 0, stream>>>(qkv, tab, kr, 4096, 1.0f);
    transpose_v<<<dim3(64, 4, 16), 256, 0, stream>>>(qkv, vt);
    transpose_cast<<<dim3(128, 128), 256, 0, stream>>>(wo, wt_o, 4096, 4096);
    attn_kernel<<<dim3(32, 64), 256, 0, stream>>>(qr, kr, vt, xb);
    gemm_bt<false><<<dim3(32, 32), 256, 0, stream>>>(xb, wt_o, (void*)out, 4096, 4096);
}

// Round 3
// 597.335 us; speedup vs baseline: 1.2099x; 1.0693x over previous
//
#include <hip/hip_runtime.h>
#include <hip/hip_bf16.h>

typedef __attribute__((ext_vector_type(8))) short short8;
typedef __attribute__((ext_vector_type(4))) float f32x4;
typedef __attribute__((ext_vector_type(16))) float f32x16;

#define GLD16(gp, lp) __builtin_amdgcn_global_load_lds( \
    (const __attribute__((address_space(1))) unsigned int*)(gp), \
    (__attribute__((address_space(3))) unsigned int*)(lp), 16, 0, 0)

static __device__ __forceinline__ float bf2f(unsigned short u) {
    union { unsigned int i; float f; } v; v.i = ((unsigned int)u) << 16; return v.f;
}
static __device__ __forceinline__ short f2bf(float f) {
    union { float f; unsigned int i; } v; v.f = f;
    unsigned int r = v.i + 0x7FFFu + ((v.i >> 16) & 1u);
    return (short)(r >> 16);
}
static __device__ __forceinline__ unsigned int pack2bf(float lo, float hi) {
    return ((unsigned int)(unsigned short)f2bf(hi) << 16) | (unsigned int)(unsigned short)f2bf(lo);
}
static __device__ __forceinline__ unsigned int cvtpk(float lo, float hi) {
    unsigned int w;
    asm("v_cvt_pk_bf16_f32 %0, %1, %2" : "=v"(w) : "v"(lo), "v"(hi));
    return w;
}

// ---------------- elementwise cast fp32 -> bf16 ----------------
__global__ void cast_f32_bf16(const float* __restrict__ src, short* __restrict__ dst, int n) {
    int i = (blockIdx.x * 256 + threadIdx.x) * 4;
    if (i >= n) return;
    float4 v = *(const float4*)(src + i);
    short4 o;
    o.x = f2bf(v.x); o.y = f2bf(v.y); o.z = f2bf(v.z); o.w = f2bf(v.w);
    *(short4*)(dst + i) = o;
}

// ---------------- transpose+cast: src fp32 (K x N) -> dst bf16 (N x K) ----------------
__global__ void transpose_cast(const float* __restrict__ src, short* __restrict__ dst,
                               int N, int dstStride) {
    __shared__ float tile[32][33];
    int k0 = blockIdx.x * 32, n0 = blockIdx.y * 32;
    int t = threadIdx.x, c = t & 31, r = t >> 5;
#pragma unroll
    for (int p = 0; p < 4; ++p)
        tile[r + p * 8][c] = src[(size_t)(k0 + r + p * 8) * N + n0 + c];
    __syncthreads();
#pragma unroll
    for (int p = 0; p < 4; ++p)
        dst[(size_t)(n0 + r + p * 8) * dstStride + k0 + c] = f2bf(tile[c][r + p * 8]);
}

// ---------------- transpose V (bf16, strided src in QKV) -> Vt [b][kvh][128][2048] ----------------
__global__ void transpose_v(const short* __restrict__ qkv, short* __restrict__ vt) {
    __shared__ short tile[32][33];
    int s0 = blockIdx.x * 32, d0 = blockIdx.y * 32;
    int bh = blockIdx.z;
    int b = bh >> 3, h = bh & 7;
    const short* src = qkv + (size_t)b * 2048 * 6144 + 5120 + h * 128;
    short* dst = vt + (size_t)bh * 128 * 2048;
    int t = threadIdx.x, c = t & 31, r = t >> 5;
#pragma unroll
    for (int p = 0; p < 4; ++p)
        tile[r + p * 8][c] = src[(size_t)(s0 + r + p * 8) * 6144 + d0 + c];
    __syncthreads();
#pragma unroll
    for (int p = 0; p < 4; ++p)
        dst[(size_t)(d0 + r + p * 8) * 2048 + s0 + c] = tile[c][r + p * 8];
}

// ---------------- rope tables: [2048][64][2] (cos,sin) ----------------
__global__ void rope_tables(float* __restrict__ cs) {
    int i = blockIdx.x * 256 + threadIdx.x;
    int s = i >> 6, d2 = i & 63;
    float inv = expf(-9.210340371976184f * (float)(2 * d2) * (1.0f / 128.0f));
    float ang = (float)s * inv;
    float sn, c;
    sincosf(ang, &sn, &c);
    cs[(size_t)i * 2] = c;
    cs[(size_t)i * 2 + 1] = sn;
}

// ---------------- rope apply + regroup ----------------
template<int NH>
__global__ void rope_apply(const short* __restrict__ qkv, const float* __restrict__ cs,
                           short* __restrict__ dst, int colOff, float scale) {
    int i = blockIdx.x * 256 + threadIdx.x;
    int d2 = i & 63;
    int t2 = i >> 6;
    int h = t2 % NH;
    int bs = t2 / NH;
    int s = bs & 2047;
    int b = bs >> 11;
    unsigned int pr = *(const unsigned int*)(qkv + (size_t)bs * 6144 + colOff + h * 128 + 2 * d2);
    float xr = bf2f((unsigned short)(pr & 0xFFFFu));
    float xi = bf2f((unsigned short)(pr >> 16));
    const float* cp = cs + ((size_t)s * 64 + d2) * 2;
    float c = cp[0], sn = cp[1];
    float outr = (xr * c - xi * sn) * scale;
    float outi = (xr * sn + xi * c) * scale;
    *(unsigned int*)(dst + ((size_t)(b * NH + h) * 2048 + s) * 128 + 2 * d2) = pack2bf(outr, outi);
}

// ---------------- GEMM: A bf16 (M x K) row-major, Bt bf16 (N x K) row-major, C = A*B ----------------
template<bool BF16OUT>
__global__ __launch_bounds__(256, 2) void gemm_bt(const short* __restrict__ A,
                                                  const short* __restrict__ Bt,
                                                  void* __restrict__ Cv,
                                                  int N, int K) {
    __shared__ short As[128 * 64];
    __shared__ short Bs[128 * 64];
    const int tid = threadIdx.x;
    const int lane = tid & 63;
    const int wid = tid >> 6;
    const int lr = lane & 15;
    const int lq = lane >> 4;
    const int m0 = blockIdx.x * 128;
    const int n0 = blockIdx.y * 128;
    const int wr = (wid >> 1) * 64;
    const int wc = (wid & 1) * 64;
    f32x4 acc[4][4];
#pragma unroll
    for (int i = 0; i < 4; ++i)
#pragma unroll
        for (int j = 0; j < 4; ++j) acc[i][j] = f32x4{0.f, 0.f, 0.f, 0.f};

    const short* aBase = A + (size_t)m0 * K;
    const short* bBase = Bt + (size_t)n0 * K;

    for (int k0 = 0; k0 < K; k0 += 64) {
#pragma unroll
        for (int j = 0; j < 4; ++j) {
            int c = (wid * 4 + j) * 64 + lane;
            int row = c >> 3;
            int cb = ((c & 7) << 4) ^ ((row & 7) << 4);
            GLD16(aBase + (size_t)row * K + k0 + (cb >> 1), As + (wid * 4 + j) * 512);
            GLD16(bBase + (size_t)row * K + k0 + (cb >> 1), Bs + (wid * 4 + j) * 512);
        }
        __syncthreads();
#pragma unroll
        for (int ks = 0; ks < 2; ++ks) {
            short8 af[4], bfr[4];
#pragma unroll
            for (int mi = 0; mi < 4; ++mi) {
                int row = wr + mi * 16 + lr;
                int cb = (ks * 64 + lq * 16) ^ ((row & 7) << 4);
                af[mi] = *(const short8*)(As + row * 64 + (cb >> 1));
            }
#pragma unroll
            for (int ni = 0; ni < 4; ++ni) {
                int row = wc + ni * 16 + lr;
                int cb = (ks * 64 + lq * 16) ^ ((row & 7) << 4);
                bfr[ni] = *(const short8*)(Bs + row * 64 + (cb >> 1));
            }
#pragma unroll
            for (int mi = 0; mi < 4; ++mi)
#pragma unroll
                for (int ni = 0; ni < 4; ++ni)
                    acc[mi][ni] = __builtin_amdgcn_mfma_f32_16x16x32_bf16(af[mi], bfr[ni], acc[mi][ni], 0, 0, 0);
        }
        __syncthreads();
    }
#pragma unroll
    for (int mi = 0; mi < 4; ++mi)
#pragma unroll
        for (int ni = 0; ni < 4; ++ni)
#pragma unroll
            for (int r = 0; r < 4; ++r) {
                int row = m0 + wr + mi * 16 + lq * 4 + r;
                int col = n0 + wc + ni * 16 + lr;
                float v = acc[mi][ni][r];
                if constexpr (BF16OUT) ((short*)Cv)[(size_t)row * N + col] = f2bf(v);
                else                   ((float*)Cv)[(size_t)row * N + col] = v;
            }
}

// ---------------- flash attention v3: 32x32 MFMA, in-register P (cvt_pk + permlane32_swap) ----------------
// Qr[b][qh][s][128] pre-scaled, Kr[b][kvh][s][128], Vt[b][kvh][128][2048]
// grid (16 qb, 64 b*qh), 4 waves x 32 q-rows (QBLK=128), KVBLK=64, causal.
// S^T = mfma32(K, Q): lane holds P^T[kv][q=lane&31], kv = (reg&3)+8*(reg>>2)+4*hi.
// O^T = mfma32(Vt, P^T): per-q softmax state is lane-local (q = lane&31).
__global__ __launch_bounds__(256, 2) void attn_kernel(const short* __restrict__ Qr,
                                                      const short* __restrict__ Kr,
                                                      const short* __restrict__ Vt,
                                                      short* __restrict__ Out) {
    __shared__ short Ks[64 * 128];   // [kv][d], 256B rows, chunk-XOR swizzled
    __shared__ short Vs[128 * 64];   // [d][kv], 128B rows, chunk-XOR swizzled
    const int qb = 15 - blockIdx.x;  // long blocks dispatch first
    const int bh = blockIdx.y;
    const int b = bh >> 5;
    const int qh = bh & 31;
    const int kvh = qh >> 2;
    const int tid = threadIdx.x;
    const int lane = tid & 63;
    const int w = tid >> 6;
    const int l31 = lane & 31;
    const int hi = lane >> 5;
    const int qg0 = qb * 128 + w * 32;          // wave's first q row

    // Q B-fragments (reg-resident): qf[ks][j] = Q[q=l31][d = ks*16 + hi*8 + j]
    const short* qbase = Qr + ((size_t)bh * 2048 + qg0 + l31) * 128 + hi * 8;
    short8 qf[8];
#pragma unroll
    for (int ks = 0; ks < 8; ++ks)
        qf[ks] = *(const short8*)(qbase + ks * 16);

    const short* kbase = Kr + (size_t)(b * 8 + kvh) * 2048 * 128;
    const short* vbase = Vt + (size_t)(b * 8 + kvh) * 128 * 2048;

    float m_run = -INFINITY, l_run = 0.0f;      // per q = l31 (replicated over hi)
    f32x16 oacc[4];                             // O^T[d-tile][q]: d = dt*32 + (reg&3)+8*(reg>>2)+4*hi
#pragma unroll
    for (int dt = 0; dt < 4; ++dt) oacc[dt] = f32x16{0,0,0,0,0,0,0,0,0,0,0,0,0,0,0,0};

    const int nkb = 2 * qb + 2;
    for (int kb = 0; kb < nkb; ++kb) {
        const int s0 = kb * 64;
        // ---- stage K (64x128) and V (128x64) into LDS, inverse-swizzled source ----
#pragma unroll
        for (int j = 0; j < 4; ++j) {
            int c = j * 256 + tid;
            int krow = c >> 4;
            int kcol = ((c & 15) ^ (krow & 7)) * 8;
            GLD16(kbase + (size_t)(s0 + krow) * 128 + kcol, Ks + (size_t)c * 8);
            int vrow = c >> 3;
            int vcol = ((c & 7) ^ (vrow & 7)) * 8;
            GLD16(vbase + (size_t)vrow * 2048 + s0 + vcol, Vs + (size_t)c * 8);
        }
        __syncthreads();

        if (s0 <= qg0 + 31) {   // wave has at least one unmasked row in this KV block
            // ---- QK^T: S^T[kv][q] = K · Q^T ----
            f32x16 st0 = f32x16{0,0,0,0,0,0,0,0,0,0,0,0,0,0,0,0};
            f32x16 st1 = f32x16{0,0,0,0,0,0,0,0,0,0,0,0,0,0,0,0};
            __builtin_amdgcn_s_setprio(1);
#pragma unroll
            for (int ks = 0; ks < 8; ++ks) {
                int row0 = l31;
                int ch0 = ((2 * ks + hi) ^ (row0 & 7)) * 8;
                short8 kf0 = *(const short8*)(Ks + row0 * 128 + ch0);
                st0 = __builtin_amdgcn_mfma_f32_32x32x16_bf16(kf0, qf[ks], st0, 0, 0, 0);
                int row1 = 32 + l31;
                int ch1 = ((2 * ks + hi) ^ (row1 & 7)) * 8;
                short8 kf1 = *(const short8*)(Ks + row1 * 128 + ch1);
                st1 = __builtin_amdgcn_mfma_f32_32x32x16_bf16(kf1, qf[ks], st1, 0, 0, 0);
            }
            __builtin_amdgcn_s_setprio(0);

            const int q = qg0 + l31;
            if (s0 + 63 > qg0) {   // causal mask needed
#pragma unroll
                for (int i = 0; i < 16; ++i) {
                    int kvr = (i & 3) + 8 * (i >> 2) + 4 * hi;
                    if (s0 + kvr > q)      st0[i] = -INFINITY;
                    if (s0 + 32 + kvr > q) st1[i] = -INFINITY;
                }
            }

            // ---- online softmax (all lane-local in q) ----
            float mx = -INFINITY;
#pragma unroll
            for (int i = 0; i < 16; ++i) mx = fmaxf(mx, fmaxf(st0[i], st1[i]));
            mx = fmaxf(mx, __shfl_xor(mx, 32, 64));

            const bool defer = __all(mx - m_run <= 8.0f);
            float mN, alpha;
            if (defer) { mN = m_run; alpha = 1.0f; }
            else       { mN = fmaxf(m_run, mx); alpha = __expf(m_run - mN); }

            float p0[16], p1[16];
            float rsum = 0.0f;
#pragma unroll
            for (int i = 0; i < 16; ++i) {
                p0[i] = __expf(st0[i] - mN);
                p1[i] = __expf(st1[i] - mN);
                rsum += p0[i] + p1[i];
            }
            rsum += __shfl_xor(rsum, 32, 64);
            l_run = l_run * alpha + rsum;
            m_run = mN;
            if (!defer) {
#pragma unroll
                for (int dt = 0; dt < 4; ++dt)
#pragma unroll
                    for (int i = 0; i < 16; ++i) oacc[dt][i] *= alpha;
            }

            // ---- assemble P^T B-fragments in-register: cvt_pk + permlane32_swap ----
            short8 pfr[4];
#pragma unroll
            for (int kvs = 0; kvs < 4; ++kvs) {
                const float* pp = (kvs < 2) ? p0 : p1;
                const int h8 = (kvs & 1) * 8;
                unsigned int x0 = cvtpk(pp[h8 + 0], pp[h8 + 1]);
                unsigned int x1 = cvtpk(pp[h8 + 2], pp[h8 + 3]);
                unsigned int y0 = cvtpk(pp[h8 + 4], pp[h8 + 5]);
                unsigned int y1 = cvtpk(pp[h8 + 6], pp[h8 + 7]);
                asm("v_permlane32_swap_b32 %0, %1" : "+v"(x0), "+v"(y0));
                asm("v_permlane32_swap_b32 %0, %1" : "+v"(x1), "+v"(y1));
                union { unsigned int u[4]; short8 s; } uu;
                uu.u[0] = x0; uu.u[1] = x1; uu.u[2] = y0; uu.u[3] = y1;
                pfr[kvs] = uu.s;
            }

            // ---- PV: O^T[d][q] += V^T · P^T ----
            __builtin_amdgcn_s_setprio(1);
#pragma unroll
            for (int dt = 0; dt < 4; ++dt) {
                int row = dt * 32 + l31;
#pragma unroll
                for (int kvs = 0; kvs < 4; ++kvs) {
                    int ch = ((2 * kvs + hi) ^ (row & 7)) * 8;
                    short8 vf = *(const short8*)(Vs + row * 64 + ch);
                    oacc[dt] = __builtin_amdgcn_mfma_f32_32x32x16_bf16(vf, pfr[kvs], oacc[dt], 0, 0, 0);
                }
            }
            __builtin_amdgcn_s_setprio(0);
        }
        __syncthreads();
    }

    // ---- epilogue: normalize (lane-local l) and store O^T transposed to Out[b,s][qh*128+d] ----
    const float inv = 1.0f / l_run;
    const size_t row = (size_t)b * 2048 + qg0 + l31;
    short* obase = Out + row * 4096 + qh * 128;
#pragma unroll
    for (int dt = 0; dt < 4; ++dt) {
#pragma unroll
        for (int g = 0; g < 4; ++g) {
            short4 o4;
            o4.x = f2bf(oacc[dt][g * 4 + 0] * inv);
            o4.y = f2bf(oacc[dt][g * 4 + 1] * inv);
            o4.z = f2bf(oacc[dt][g * 4 + 2] * inv);
            o4.w = f2bf(oacc[dt][g * 4 + 3] * inv);
            *(short4*)(obase + dt * 32 + g * 8 + hi * 4) = o4;
        }
    }
}

// ---------------- workspace layout (bytes) ----------------
// WT_QKV  @ 0          : 6144x4096 bf16 = 50331648
// XB      @ 50331648   : 4096x4096 bf16 = 33554432   (reused as attn output)
// QKV     @ 83886080   : 4096x6144 bf16 = 50331648   (first 33.5MB reused as WT_O)
// QR      @ 134217728  : 2*32*2048*128 bf16 = 33554432
// KR      @ 167772160  : 2*8*2048*128 bf16 = 8388608
// VT      @ 176160768  : 2*8*128*2048 bf16 = 8388608
// TAB     @ 184549376  : 2048*64*2 fp32 = 1048576    -> total 185597952

extern "C" void kernel_launch(void* const* d_in, const int* in_sizes, int n_in,
                              void* d_out, int out_size, void* d_ws, size_t ws_size,
                              hipStream_t stream) {
    const float* x  = (const float*)d_in[0];
    const float* wq = (const float*)d_in[1];
    const float* wk = (const float*)d_in[2];
    const float* wv = (const float*)d_in[3];
    const float* wo = (const float*)d_in[4];
    float* out = (float*)d_out;
    char* ws = (char*)d_ws;

    short* wt_qkv = (short*)(ws + 0);
    short* xb     = (short*)(ws + 50331648);
    short* qkv    = (short*)(ws + 83886080);
    short* wt_o   = (short*)(ws + 83886080);
    short* qr     = (short*)(ws + 134217728);
    short* kr     = (short*)(ws + 167772160);
    short* vt     = (short*)(ws + 176160768);
    float* tab    = (float*)(ws + 184549376);

    cast_f32_bf16<<<16384, 256, 0, stream>>>(x, xb, 16777216);
    transpose_cast<<<dim3(128, 128), 256, 0, stream>>>(wq, wt_qkv, 4096, 4096);
    transpose_cast<<<dim3(128, 32),  256, 0, stream>>>(wk, wt_qkv + (size_t)4096 * 4096, 1024, 4096);
    transpose_cast<<<dim3(128, 32),  256, 0, stream>>>(wv, wt_qkv + (size_t)5120 * 4096, 1024, 4096);
    rope_tables<<<512, 256, 0, stream>>>(tab);
    gemm_bt<true><<<dim3(32, 48), 256, 0, stream>>>(xb, wt_qkv, (void*)qkv, 6144, 4096);
    rope_apply<32><<<32768, 256, 0, stream>>>(qkv, tab, qr, 0, 0.08838834764831845f);
    rope_apply<8><<<8192, 256, 0, stream>>>(qkv, tab, kr, 4096, 1.0f);
    transpose_v<<<dim3(64, 4, 16), 256, 0, stream>>>(qkv, vt);
    transpose_cast<<<dim3(128, 128), 256, 0, stream>>>(wo, wt_o, 4096, 4096);
    attn_kernel<<<dim3(16, 64), 256, 0, stream>>>(qr, kr, vt, xb);
    gemm_bt<false><<<dim3(32, 32), 256, 0, stream>>>(xb, wt_o, (void*)out, 4096, 4096);
}